// Round 1
// baseline (39488.416 us; speedup 1.0000x reference)
//
#include <hip/hip_runtime.h>
#include <stdint.h>

// ---------------------------------------------------------------------------
// mLSTM block on MI355X.
// Phase A: cast x/weights to bf16; GEMM [Wx|Ax] = x @ [W_w;A_w]^T + (W_b+U_b|0)
// Phase B: persistent cooperative recurrence: 4 groups (16 batches) x 32 blocks
//          (16 hidden units). U/B_w fragments persistent in VGPRs; h exchanged
//          via global bf16 double-buffer + per-group atomic barrier.
// ws layout (bytes):
//   0         x_bf16   [65536][512]        67,108,864
//   67108864  Wc_bf16  [2176][512]          2,228,224   (W_w rows 0..2047, A_w 2048..2111, zeros)
//   69337088  bias     [2176] f32               8,704   (W_b+U_b, 0 for Ax)
//   69345792  U_bf16   [2048][512]          2,097,152
//   71442944  Bw_bf16  [64][512]               65,536
//   71508480  P_bf16   [512][64] (x0.1)        65,536
//   71574016  hbuf     [2][64][512] bf16      131,072
//   71705088  cnt      4 groups x 256B          1,024
//   71706112  Wxc_bf16 [65536][2112]       276,824,064
//   total 348,530,176  (ws_size must be >= this)
// ---------------------------------------------------------------------------

typedef float    f32x4  __attribute__((ext_vector_type(4)));
typedef __bf16   bf16x8 __attribute__((ext_vector_type(8)));
typedef uint16_t u16;
typedef uint16_t u16x8  __attribute__((ext_vector_type(8)));

#define WS_XB     0
#define WS_WC     67108864
#define WS_BIAS   69337088
#define WS_U      69345792
#define WS_BW     71442944
#define WS_P      71508480
#define WS_HBUF   71574016
#define WS_CNT    71705088
#define WS_WXC    71706112

#define OUT_OUTS  33554432   // 64*1024*512
#define OUT_H     33554432
#define OUT_C     33587200   // +32768

#define SMEM_BYTES (16384 + 4352 + 4352 + 1088)

__device__ __forceinline__ u16 f2bf(float f) {
  uint32_t u = __builtin_bit_cast(uint32_t, f);
  u = (u + 0x7fffu + ((u >> 16) & 1u)) >> 16;
  return (u16)u;
}
__device__ __forceinline__ float bf2f(u16 b) {
  uint32_t u = ((uint32_t)b) << 16;
  return __builtin_bit_cast(float, u);
}
__device__ __forceinline__ f32x4 mfma16(u16x8 a, u16x8 b, f32x4 c) {
  return __builtin_amdgcn_mfma_f32_16x16x32_bf16(
      __builtin_bit_cast(bf16x8, a), __builtin_bit_cast(bf16x8, b), c, 0, 0, 0);
}
__device__ __forceinline__ float sigm(float x) { return 1.f / (1.f + __expf(-x)); }
__device__ __forceinline__ float tanh_fast(float x) {
  float a = fabsf(x);
  float e = __expf(2.f * a);
  float t = 1.f - 2.f / (e + 1.f);
  return x < 0.f ? -t : t;
}

// ---------------- Phase A: casts ----------------
__global__ void cast_x(const float* __restrict__ x, u16* __restrict__ xb) {
  int i = blockIdx.x * 256 + threadIdx.x;          // 4,194,304 threads, 8 elems each
  const float4* src = (const float4*)x;
  float4 a = src[(size_t)i * 2];
  float4 b = src[(size_t)i * 2 + 1];
  u16x8 o;
  o[0] = f2bf(a.x); o[1] = f2bf(a.y); o[2] = f2bf(a.z); o[3] = f2bf(a.w);
  o[4] = f2bf(b.x); o[5] = f2bf(b.y); o[6] = f2bf(b.z); o[7] = f2bf(b.w);
  *(u16x8*)(xb + (size_t)i * 8) = o;
}

__global__ void prep(const float* __restrict__ W_w, const float* __restrict__ W_b,
                     const float* __restrict__ U_w, const float* __restrict__ U_b,
                     const float* __restrict__ A_w, const float* __restrict__ B_w,
                     const float* __restrict__ P_w,
                     u16* __restrict__ Wc, float* __restrict__ bias,
                     u16* __restrict__ Ubf, u16* __restrict__ Bwbf,
                     u16* __restrict__ Pbf, int* __restrict__ cnt) {
  const int total = 1114112 + 1048576 + 32768 + 32768 + 2176 + 256;
  for (int i = blockIdx.x * blockDim.x + threadIdx.x; i < total;
       i += gridDim.x * blockDim.x) {
    int idx = i;
    if (idx < 1114112) {                            // Wc [2176][512]
      int row = idx >> 9, k = idx & 511;
      float v = 0.f;
      if (row < 2048) v = W_w[row * 512 + k];
      else if (row < 2112) v = A_w[(row - 2048) * 512 + k];
      Wc[idx] = f2bf(v);
      continue;
    }
    idx -= 1114112;
    if (idx < 1048576) { Ubf[idx] = f2bf(U_w[idx]); continue; }
    idx -= 1048576;
    if (idx < 32768) { Bwbf[idx] = f2bf(B_w[idx]); continue; }
    idx -= 32768;
    if (idx < 32768) { Pbf[idx] = f2bf(0.1f * P_w[idx]); continue; }
    idx -= 32768;
    if (idx < 2176) {
      bias[idx] = (idx < 2048) ? (W_b[idx] + U_b[idx]) : 0.f;
      continue;
    }
    idx -= 2176;
    cnt[idx] = 0;                                   // 256 ints (4 groups, 256B apart)
  }
}

// ---------------- Phase A: big GEMM  out[m][n] = sum_k xb[m][k]*Wc[n][k] + bias[n]
__global__ void __launch_bounds__(256) gemm_wxc(const u16* __restrict__ xb,
                                                const u16* __restrict__ Wc,
                                                const float* __restrict__ bias,
                                                u16* __restrict__ outWx) {
  __shared__ u16 Atile[128 * 64];
  __shared__ u16 Btile[128 * 64];
  const int n0 = blockIdx.x * 128;
  const int m0 = blockIdx.y * 128;
  const int tid = threadIdx.x, ln = tid & 63, wv = tid >> 6;
  const int wm = (wv >> 1) * 64, wn = (wv & 1) * 64;
  f32x4 acc[4][4] = {};

  for (int k0 = 0; k0 < 512; k0 += 64) {
    __syncthreads();
    #pragma unroll
    for (int q = 0; q < 4; ++q) {                   // 1024 chunks of 16B per tile
      int idx = tid + q * 256;
      int row = idx >> 3, kc = idx & 7;
      uint4 va = *(const uint4*)(xb + (size_t)(m0 + row) * 512 + k0 + kc * 8);
      *(uint4*)((char*)Atile + row * 128 + ((kc * 16) ^ ((row & 7) << 4))) = va;
      uint4 vb = *(const uint4*)(Wc + (size_t)(n0 + row) * 512 + k0 + kc * 8);
      *(uint4*)((char*)Btile + row * 128 + ((kc * 16) ^ ((row & 7) << 4))) = vb;
    }
    __syncthreads();
    #pragma unroll
    for (int kk = 0; kk < 64; kk += 32) {
      u16x8 af[4], bf[4];
      const int kb = kk * 2 + ((ln >> 4) << 4);
      #pragma unroll
      for (int i = 0; i < 4; ++i) {
        int arow = wm + i * 16 + (ln & 15);
        af[i] = *(const u16x8*)((char*)Atile + arow * 128 + (kb ^ ((arow & 7) << 4)));
        int brow = wn + i * 16 + (ln & 15);
        bf[i] = *(const u16x8*)((char*)Btile + brow * 128 + (kb ^ ((brow & 7) << 4)));
      }
      #pragma unroll
      for (int i = 0; i < 4; ++i)
        #pragma unroll
        for (int j = 0; j < 4; ++j)
          acc[i][j] = mfma16(af[i], bf[j], acc[i][j]);
    }
  }
  #pragma unroll
  for (int i = 0; i < 4; ++i) {
    const int mrow = m0 + wm + i * 16 + ((ln >> 4) << 2);
    #pragma unroll
    for (int j = 0; j < 4; ++j) {
      const int n = n0 + wn + j * 16 + (ln & 15);
      if (n < 2112) {
        const float bv = bias[n];
        #pragma unroll
        for (int r = 0; r < 4; ++r)
          outWx[(size_t)(mrow + r) * 2112 + n] = f2bf(acc[i][j][r] + bv);
      }
    }
  }
}

// ---------------- Phase B: persistent recurrence ----------------
// grid 128 blocks x 512 thr. group = bid&3 (16 batches), ublk = bid>>2 (16 units).
// waves 0..3: gate chunks i,f,o,g (16 U-rows each); waves 4..7: v = h@Bw^T tiles.
__global__ void __launch_bounds__(512) recurrent(const u16* __restrict__ Wxc,
                                                 const u16* __restrict__ Ubf,
                                                 const u16* __restrict__ Bwbf,
                                                 const u16* __restrict__ Pbf,
                                                 u16* __restrict__ hbuf,
                                                 int* __restrict__ cnt,
                                                 float* __restrict__ out) {
  extern __shared__ char smem[];
  char*  h_lds   = smem;                                  // [16][512] bf16 swizzled
  float* v_buf   = (float*)(smem + 16384);                // [16][68]
  float* g_buf   = (float*)(smem + 16384 + 4352);         // [4][16][17]
  float* mix_buf = (float*)(smem + 16384 + 4352 + 4352);  // [16][17]

  const int tid = threadIdx.x;
  const int wv  = tid >> 6;
  const int ln  = tid & 63;
  const int grp = blockIdx.x & 3;
  const int ublk = blockIdx.x >> 2;
  const int u0 = ublk << 4;
  const int b0 = grp << 4;

  // persistent B-operand fragments in VGPRs (loaded once)
  u16x8 bfrag[16];
  {
    const u16* src = (wv < 4)
        ? (Ubf + (size_t)(wv * 512 + u0 + (ln & 15)) * 512)
        : (Bwbf + (size_t)((wv - 4) * 16 + (ln & 15)) * 512);
    #pragma unroll
    for (int ks = 0; ks < 16; ++ks)
      bfrag[ks] = *(const u16x8*)(src + ks * 32 + ((ln >> 4) << 3));
  }
  u16x8 pfrag[2];
  #pragma unroll
  for (int ks = 0; ks < 2; ++ks)
    pfrag[ks] = *(const u16x8*)(Pbf + (size_t)(u0 + (ln & 15)) * 64 + ks * 32 + ((ln >> 4) << 3));

  for (int i = tid; i < 1024; i += 512) ((uint4*)h_lds)[i] = make_uint4(0, 0, 0, 0);

  const int arow_base = (ln & 15) * 1024;
  const int a_xor = (ln & 7) << 4;
  const int a_k0 = (ln >> 4) << 4;
  const int myb = tid >> 4, myu = tid & 15;   // elementwise mapping (tid<256)
  float c_reg = 0.f, h_last = 0.f;

  __syncthreads();

  #pragma unroll 1
  for (int t = 0; t < 1024; ++t) {
    // early independent global loads (Wx_t slice, Ax_t slice)
    u16 wxu[4];
    if (wv < 4) {
      const int col = wv * 512 + u0 + (ln & 15);
      const size_t rb = ((size_t)(b0 + ((ln >> 4) << 2)) * 1024 + t) * 2112;
      #pragma unroll
      for (int j = 0; j < 4; ++j) wxu[j] = Wxc[rb + (size_t)j * 1024 * 2112 + col];
    }
    u16x8 axu0, axu1;
    if (wv == 0) {
      const u16* axp = Wxc + ((size_t)(b0 + (ln & 15)) * 1024 + t) * 2112 + 2048 + ((ln >> 4) << 3);
      axu0 = *(const u16x8*)(axp);
      axu1 = *(const u16x8*)(axp + 32);
    }

    // K-loop: gates (wv<4) or v (wv>=4); A = h [16 x 512] from LDS
    f32x4 acc = {0.f, 0.f, 0.f, 0.f};
    #pragma unroll
    for (int ks = 0; ks < 16; ++ks) {
      const int kb = ks * 64 + a_k0;
      u16x8 afr = *(const u16x8*)(h_lds + arow_base + (kb ^ a_xor));
      acc = mfma16(afr, bfrag[ks], acc);
    }

    if (wv >= 4) {
      const int r = ((wv - 4) << 4) + (ln & 15);
      const int br = (ln >> 4) << 2;
      #pragma unroll
      for (int j = 0; j < 4; ++j) v_buf[(br + j) * 68 + r] = acc[j];
    } else {
      const int gi = wv * 272 + (ln & 15);
      const int br = (ln >> 4) << 2;
      #pragma unroll
      for (int j = 0; j < 4; ++j) {
        float g = acc[j] + bf2f(wxu[j]);
        g = (wv == 3) ? tanh_fast(g) : sigm(g);
        g_buf[gi + (br + j) * 17] = g;
      }
    }
    __syncthreads();

    // mix = (ax .* v) @ P'^T for this block's 16 units (wave 0)
    if (wv == 0) {
      f32x4 accm = {0.f, 0.f, 0.f, 0.f};
      const int bb = ln & 15;
      const int r0 = (ln >> 4) << 3;
      u16x8 af;
      #pragma unroll
      for (int i = 0; i < 8; ++i)
        af[i] = f2bf(bf2f(axu0[i]) * v_buf[bb * 68 + r0 + i]);
      accm = mfma16(af, pfrag[0], accm);
      #pragma unroll
      for (int i = 0; i < 8; ++i)
        af[i] = f2bf(bf2f(axu1[i]) * v_buf[bb * 68 + 32 + r0 + i]);
      accm = mfma16(af, pfrag[1], accm);
      const int br = (ln >> 4) << 2;
      #pragma unroll
      for (int j = 0; j < 4; ++j) mix_buf[(br + j) * 17 + bb] = accm[j];
    }
    __syncthreads();

    // elementwise cell update; c in fp32 registers
    if (tid < 256) {
      const int go = myb * 17 + myu;
      float iv = g_buf[go];
      float fv = g_buf[272 + go];
      float ov = g_buf[544 + go];
      float gv = g_buf[816 + go];
      float mx = mix_buf[go];
      c_reg = fv * c_reg + iv * gv + mx;     // 0.1 folded into P
      float h = ov * tanh_fast(c_reg);
      h_last = h;
      out[((size_t)(b0 + myb) * 1024 + t) * 512 + u0 + myu] = h;
      hbuf[(size_t)(t & 1) * 32768 + (size_t)(b0 + myb) * 512 + u0 + myu] = f2bf(h);
    }

    // group barrier: release h stores, arrive, spin, acquire
    __threadfence();
    __syncthreads();
    if (tid == 0) {
      __hip_atomic_fetch_add(cnt + grp * 64, 1, __ATOMIC_RELEASE, __HIP_MEMORY_SCOPE_AGENT);
      const int target = 32 * (t + 1);
      while (__hip_atomic_load(cnt + grp * 64, __ATOMIC_ACQUIRE, __HIP_MEMORY_SCOPE_AGENT) < target) {}
    }
    __syncthreads();
    __threadfence();

    // stage h_t (full group slice) into swizzled LDS for next step
    {
      const uint4* src = (const uint4*)(hbuf + (size_t)(t & 1) * 32768 + (size_t)b0 * 512);
      #pragma unroll
      for (int q = 0; q < 2; ++q) {
        int idx = tid + q * 512;
        int row = idx >> 6, kc = idx & 63;
        uint4 val = src[idx];
        *(uint4*)(h_lds + row * 1024 + ((kc * 16) ^ ((row & 7) << 4))) = val;
      }
    }
    __syncthreads();
  }

  if (tid < 256) {
    out[OUT_H + (size_t)(b0 + myb) * 512 + u0 + myu] = h_last;
    out[OUT_C + (size_t)(b0 + myb) * 512 + u0 + myu] = c_reg;
  }
}

// ---------------------------------------------------------------------------
extern "C" void kernel_launch(void* const* d_in, const int* in_sizes, int n_in,
                              void* d_out, int out_size, void* d_ws, size_t ws_size,
                              hipStream_t stream) {
  const float* x   = (const float*)d_in[0];
  const float* W_w = (const float*)d_in[1];
  const float* W_b = (const float*)d_in[2];
  const float* U_w = (const float*)d_in[3];
  const float* U_b = (const float*)d_in[4];
  const float* A_w = (const float*)d_in[5];
  const float* B_w = (const float*)d_in[6];
  const float* P_w = (const float*)d_in[7];
  char* ws = (char*)d_ws;

  u16*   xb   = (u16*)(ws + WS_XB);
  u16*   Wc   = (u16*)(ws + WS_WC);
  float* bias = (float*)(ws + WS_BIAS);
  u16*   Ubf  = (u16*)(ws + WS_U);
  u16*   Bwbf = (u16*)(ws + WS_BW);
  u16*   Pbf  = (u16*)(ws + WS_P);
  u16*   hbuf = (u16*)(ws + WS_HBUF);
  int*   cnt  = (int*)(ws + WS_CNT);
  u16*   Wxc  = (u16*)(ws + WS_WXC);
  float* outp = (float*)d_out;

  cast_x<<<16384, 256, 0, stream>>>(x, xb);
  prep<<<2048, 256, 0, stream>>>(W_w, W_b, U_w, U_b, A_w, B_w, P_w,
                                 Wc, bias, Ubf, Bwbf, Pbf, cnt);
  gemm_wxc<<<dim3(17, 512), 256, 0, stream>>>(xb, Wc, bias, Wxc);

  void* args[] = { &Wxc, &Ubf, &Bwbf, &Pbf, &hbuf, &cnt, &outp };
  hipError_t e = hipLaunchCooperativeKernel((const void*)recurrent, dim3(128),
                                            dim3(512), args, SMEM_BYTES, stream);
  if (e != hipSuccess) {
    // 128 blocks / 256 CUs with modest LDS+VGPR: co-residency is guaranteed in
    // practice; fall back to a plain launch if cooperative capture is refused.
    recurrent<<<dim3(128), dim3(512), SMEM_BYTES, stream>>>(Wxc, Ubf, Bwbf, Pbf,
                                                            hbuf, cnt, outp);
  }
}

// Round 2
// 3995.937 us; speedup vs baseline: 9.8821x; 9.8821x over previous
//
#include <hip/hip_runtime.h>
#include <stdint.h>

// ---------------------------------------------------------------------------
// mLSTM block on MI355X.
// Phase A: cast x/weights to bf16; GEMM [Wx|Ax] = x @ [W_w;A_w]^T + (W_b+U_b|0)
// Phase B: persistent cooperative recurrence: 4 groups (16 batches) x 32 blocks
//          (16 hidden units). U/B_w fragments persistent in VGPRs; h exchanged
//          via Infinity-Cache-coherent relaxed agent atomics (sc1, NO L2
//          writeback/invalidate -- the round-1 39ms was acquire/release fences
//          emitting buffer_wbl2/buffer_inv every step/poll).
// ws layout (bytes):
//   0         x_bf16   [65536][512]        67,108,864
//   67108864  Wc_bf16  [2176][512]          2,228,224
//   69337088  bias     [2176] f32               8,704
//   69345792  U_bf16   [2048][512]          2,097,152
//   71442944  Bw_bf16  [64][512]               65,536
//   71508480  P_bf16   [512][64] (x0.1)        65,536
//   71574016  hbuf     [2][64][512] bf16      131,072
//   71705088  cnt      4 groups x 256B          1,024
//   71706112  Wxc_bf16 [65536][2112]       276,824,064
// ---------------------------------------------------------------------------

typedef float    f32x4  __attribute__((ext_vector_type(4)));
typedef __bf16   bf16x8 __attribute__((ext_vector_type(8)));
typedef uint16_t u16;
typedef uint16_t u16x8  __attribute__((ext_vector_type(8)));

#define WS_XB     0
#define WS_WC     67108864
#define WS_BIAS   69337088
#define WS_U      69345792
#define WS_BW     71442944
#define WS_P      71508480
#define WS_HBUF   71574016
#define WS_CNT    71705088
#define WS_WXC    71706112

#define OUT_H     33554432
#define OUT_C     33587200

#define SMEM_BYTES (16384 + 4352 + 4352 + 1088)

__device__ __forceinline__ u16 f2bf(float f) {
  uint32_t u = __builtin_bit_cast(uint32_t, f);
  u = (u + 0x7fffu + ((u >> 16) & 1u)) >> 16;
  return (u16)u;
}
__device__ __forceinline__ float bf2f(u16 b) {
  uint32_t u = ((uint32_t)b) << 16;
  return __builtin_bit_cast(float, u);
}
__device__ __forceinline__ f32x4 mfma16(u16x8 a, u16x8 b, f32x4 c) {
  return __builtin_amdgcn_mfma_f32_16x16x32_bf16(
      __builtin_bit_cast(bf16x8, a), __builtin_bit_cast(bf16x8, b), c, 0, 0, 0);
}
__device__ __forceinline__ float sigm(float x) { return 1.f / (1.f + __expf(-x)); }
__device__ __forceinline__ float tanh_fast(float x) {
  float a = fabsf(x);
  float e = __expf(2.f * a);
  float t = 1.f - 2.f / (e + 1.f);
  return x < 0.f ? -t : t;
}

// ---------------- Phase A: casts ----------------
__global__ void cast_x(const float* __restrict__ x, u16* __restrict__ xb) {
  int i = blockIdx.x * 256 + threadIdx.x;
  const float4* src = (const float4*)x;
  float4 a = src[(size_t)i * 2];
  float4 b = src[(size_t)i * 2 + 1];
  u16x8 o;
  o[0] = f2bf(a.x); o[1] = f2bf(a.y); o[2] = f2bf(a.z); o[3] = f2bf(a.w);
  o[4] = f2bf(b.x); o[5] = f2bf(b.y); o[6] = f2bf(b.z); o[7] = f2bf(b.w);
  *(u16x8*)(xb + (size_t)i * 8) = o;
}

__global__ void prep(const float* __restrict__ W_w, const float* __restrict__ W_b,
                     const float* __restrict__ U_w, const float* __restrict__ U_b,
                     const float* __restrict__ A_w, const float* __restrict__ B_w,
                     const float* __restrict__ P_w,
                     u16* __restrict__ Wc, float* __restrict__ bias,
                     u16* __restrict__ Ubf, u16* __restrict__ Bwbf,
                     u16* __restrict__ Pbf, int* __restrict__ cnt) {
  const int total = 1114112 + 1048576 + 32768 + 32768 + 2176 + 256;
  for (int i = blockIdx.x * blockDim.x + threadIdx.x; i < total;
       i += gridDim.x * blockDim.x) {
    int idx = i;
    if (idx < 1114112) {                            // Wc [2176][512]
      int row = idx >> 9, k = idx & 511;
      float v = 0.f;
      if (row < 2048) v = W_w[row * 512 + k];
      else if (row < 2112) v = A_w[(row - 2048) * 512 + k];
      Wc[idx] = f2bf(v);
      continue;
    }
    idx -= 1114112;
    if (idx < 1048576) { Ubf[idx] = f2bf(U_w[idx]); continue; }
    idx -= 1048576;
    if (idx < 32768) { Bwbf[idx] = f2bf(B_w[idx]); continue; }
    idx -= 32768;
    if (idx < 32768) { Pbf[idx] = f2bf(0.1f * P_w[idx]); continue; }
    idx -= 32768;
    if (idx < 2176) {
      bias[idx] = (idx < 2048) ? (W_b[idx] + U_b[idx]) : 0.f;
      continue;
    }
    idx -= 2176;
    cnt[idx] = 0;
  }
}

// ---------------- Phase A: big GEMM ----------------
__global__ void __launch_bounds__(256) gemm_wxc(const u16* __restrict__ xb,
                                                const u16* __restrict__ Wc,
                                                const float* __restrict__ bias,
                                                u16* __restrict__ outWx) {
  __shared__ u16 Atile[128 * 64];
  __shared__ u16 Btile[128 * 64];
  const int n0 = blockIdx.x * 128;
  const int m0 = blockIdx.y * 128;
  const int tid = threadIdx.x, ln = tid & 63, wv = tid >> 6;
  const int wm = (wv >> 1) * 64, wn = (wv & 1) * 64;
  f32x4 acc[4][4] = {};

  for (int k0 = 0; k0 < 512; k0 += 64) {
    __syncthreads();
    #pragma unroll
    for (int q = 0; q < 4; ++q) {
      int idx = tid + q * 256;
      int row = idx >> 3, kc = idx & 7;
      uint4 va = *(const uint4*)(xb + (size_t)(m0 + row) * 512 + k0 + kc * 8);
      *(uint4*)((char*)Atile + row * 128 + ((kc * 16) ^ ((row & 7) << 4))) = va;
      uint4 vb = *(const uint4*)(Wc + (size_t)(n0 + row) * 512 + k0 + kc * 8);
      *(uint4*)((char*)Btile + row * 128 + ((kc * 16) ^ ((row & 7) << 4))) = vb;
    }
    __syncthreads();
    #pragma unroll
    for (int kk = 0; kk < 64; kk += 32) {
      u16x8 af[4], bf[4];
      const int kb = kk * 2 + ((ln >> 4) << 4);
      #pragma unroll
      for (int i = 0; i < 4; ++i) {
        int arow = wm + i * 16 + (ln & 15);
        af[i] = *(const u16x8*)((char*)Atile + arow * 128 + (kb ^ ((arow & 7) << 4)));
        int brow = wn + i * 16 + (ln & 15);
        bf[i] = *(const u16x8*)((char*)Btile + brow * 128 + (kb ^ ((brow & 7) << 4)));
      }
      #pragma unroll
      for (int i = 0; i < 4; ++i)
        #pragma unroll
        for (int j = 0; j < 4; ++j)
          acc[i][j] = mfma16(af[i], bf[j], acc[i][j]);
    }
  }
  #pragma unroll
  for (int i = 0; i < 4; ++i) {
    const int mrow = m0 + wm + i * 16 + ((ln >> 4) << 2);
    #pragma unroll
    for (int j = 0; j < 4; ++j) {
      const int n = n0 + wn + j * 16 + (ln & 15);
      if (n < 2112) {
        const float bv = bias[n];
        #pragma unroll
        for (int r = 0; r < 4; ++r)
          outWx[(size_t)(mrow + r) * 2112 + n] = f2bf(acc[i][j][r] + bv);
      }
    }
  }
}

// ---------------- Phase B: persistent recurrence ----------------
__global__ void __launch_bounds__(512) recurrent(const u16* __restrict__ Wxc,
                                                 const u16* __restrict__ Ubf,
                                                 const u16* __restrict__ Bwbf,
                                                 const u16* __restrict__ Pbf,
                                                 u16* __restrict__ hbuf,
                                                 int* __restrict__ cnt,
                                                 float* __restrict__ out) {
  extern __shared__ char smem[];
  char*  h_lds   = smem;                                  // [16][512] bf16 swizzled
  float* v_buf   = (float*)(smem + 16384);                // [16][68]
  float* g_buf   = (float*)(smem + 16384 + 4352);         // [4][16][17]
  float* mix_buf = (float*)(smem + 16384 + 4352 + 4352);  // [16][17]

  const int tid = threadIdx.x;
  const int wv  = tid >> 6;
  const int ln  = tid & 63;
  const int grp = blockIdx.x & 3;
  const int ublk = blockIdx.x >> 2;
  const int u0 = ublk << 4;
  const int b0 = grp << 4;

  // persistent B-operand fragments in VGPRs (loaded once)
  u16x8 bfrag[16];
  {
    const u16* src = (wv < 4)
        ? (Ubf + (size_t)(wv * 512 + u0 + (ln & 15)) * 512)
        : (Bwbf + (size_t)((wv - 4) * 16 + (ln & 15)) * 512);
    #pragma unroll
    for (int ks = 0; ks < 16; ++ks)
      bfrag[ks] = *(const u16x8*)(src + ks * 32 + ((ln >> 4) << 3));
  }
  u16x8 pfrag[2];
  #pragma unroll
  for (int ks = 0; ks < 2; ++ks)
    pfrag[ks] = *(const u16x8*)(Pbf + (size_t)(u0 + (ln & 15)) * 64 + ks * 32 + ((ln >> 4) << 3));

  for (int i = tid; i < 1024; i += 512) ((uint4*)h_lds)[i] = make_uint4(0, 0, 0, 0);

  const int arow_base = (ln & 15) * 1024;
  const int a_xor = (ln & 7) << 4;
  const int a_k0 = (ln >> 4) << 4;
  const int myb = tid >> 4, myu = tid & 15;
  float c_reg = 0.f, h_last = 0.f;

  __syncthreads();

  #pragma unroll 1
  for (int t = 0; t < 1024; ++t) {
    // early independent global loads (Wx_t slice, Ax_t slice)
    u16 wxu[4];
    if (wv < 4) {
      const int col = wv * 512 + u0 + (ln & 15);
      const size_t rb = ((size_t)(b0 + ((ln >> 4) << 2)) * 1024 + t) * 2112;
      #pragma unroll
      for (int j = 0; j < 4; ++j) wxu[j] = Wxc[rb + (size_t)j * 1024 * 2112 + col];
    }
    u16x8 axu0, axu1;
    if (wv == 0) {
      const u16* axp = Wxc + ((size_t)(b0 + (ln & 15)) * 1024 + t) * 2112 + 2048 + ((ln >> 4) << 3);
      axu0 = *(const u16x8*)(axp);
      axu1 = *(const u16x8*)(axp + 32);
    }

    // K-loop: gates (wv<4) or v (wv>=4); A = h [16 x 512] from LDS
    f32x4 acc = {0.f, 0.f, 0.f, 0.f};
    #pragma unroll
    for (int ks = 0; ks < 16; ++ks) {
      const int kb = ks * 64 + a_k0;
      u16x8 afr = *(const u16x8*)(h_lds + arow_base + (kb ^ a_xor));
      acc = mfma16(afr, bfrag[ks], acc);
    }

    if (wv >= 4) {
      const int r = ((wv - 4) << 4) + (ln & 15);
      const int br = (ln >> 4) << 2;
      #pragma unroll
      for (int j = 0; j < 4; ++j) v_buf[(br + j) * 68 + r] = acc[j];
    } else {
      const int gi = wv * 272 + (ln & 15);
      const int br = (ln >> 4) << 2;
      #pragma unroll
      for (int j = 0; j < 4; ++j) {
        float g = acc[j] + bf2f(wxu[j]);
        g = (wv == 3) ? tanh_fast(g) : sigm(g);
        g_buf[gi + (br + j) * 17] = g;
      }
    }
    __syncthreads();

    // mix = (ax .* v) @ P'^T for this block's 16 units (wave 0)
    if (wv == 0) {
      f32x4 accm = {0.f, 0.f, 0.f, 0.f};
      const int bb = ln & 15;
      const int r0 = (ln >> 4) << 3;
      u16x8 af;
      #pragma unroll
      for (int i = 0; i < 8; ++i)
        af[i] = f2bf(bf2f(axu0[i]) * v_buf[bb * 68 + r0 + i]);
      accm = mfma16(af, pfrag[0], accm);
      #pragma unroll
      for (int i = 0; i < 8; ++i)
        af[i] = f2bf(bf2f(axu1[i]) * v_buf[bb * 68 + 32 + r0 + i]);
      accm = mfma16(af, pfrag[1], accm);
      const int br = (ln >> 4) << 2;
      #pragma unroll
      for (int j = 0; j < 4; ++j) mix_buf[(br + j) * 17 + bb] = accm[j];
    }
    __syncthreads();

    // elementwise cell update; c in fp32 registers; h published via
    // relaxed agent-scope atomic store (sc1 write-through to IC, no fences)
    if (tid < 256) {
      const int go = myb * 17 + myu;
      float iv = g_buf[go];
      float fv = g_buf[272 + go];
      float ov = g_buf[544 + go];
      float gv = g_buf[816 + go];
      float mx = mix_buf[go];
      c_reg = fv * c_reg + iv * gv + mx;     // 0.1 folded into P
      float h = ov * tanh_fast(c_reg);
      h_last = h;
      out[((size_t)(b0 + myb) * 1024 + t) * 512 + u0 + myu] = h;
      __hip_atomic_store(hbuf + (size_t)(t & 1) * 32768 + (size_t)(b0 + myb) * 512 + u0 + myu,
                         f2bf(h), __ATOMIC_RELAXED, __HIP_MEMORY_SCOPE_AGENT);
    }

    // group barrier: per-wave drain of sc1 stores (they are at the coherent
    // point once vmcnt retires), block barrier, then relaxed counter ops.
    // NO release/acquire -> no buffer_wbl2 / buffer_inv.
    asm volatile("s_waitcnt vmcnt(0)" ::: "memory");
    __syncthreads();
    if (tid == 0) {
      __hip_atomic_fetch_add(cnt + grp * 64, 1, __ATOMIC_RELAXED, __HIP_MEMORY_SCOPE_AGENT);
      const int target = 32 * (t + 1);
      while (__hip_atomic_load(cnt + grp * 64, __ATOMIC_RELAXED, __HIP_MEMORY_SCOPE_AGENT) < target) {}
    }
    __syncthreads();

    // stage h_t (full group slice) into swizzled LDS for next step via
    // relaxed agent-scope u64 loads (bypass possibly-stale L1/L2)
    {
      const unsigned long long* src =
          (const unsigned long long*)(hbuf + (size_t)(t & 1) * 32768 + (size_t)b0 * 512);
      #pragma unroll
      for (int q = 0; q < 2; ++q) {
        int idx = tid + q * 512;
        int row = idx >> 6, kc = idx & 63;
        unsigned long long lo = __hip_atomic_load(src + (size_t)idx * 2,
                                                  __ATOMIC_RELAXED, __HIP_MEMORY_SCOPE_AGENT);
        unsigned long long hi = __hip_atomic_load(src + (size_t)idx * 2 + 1,
                                                  __ATOMIC_RELAXED, __HIP_MEMORY_SCOPE_AGENT);
        uint4 val;
        val.x = (uint32_t)lo; val.y = (uint32_t)(lo >> 32);
        val.z = (uint32_t)hi; val.w = (uint32_t)(hi >> 32);
        *(uint4*)(h_lds + row * 1024 + ((kc * 16) ^ ((row & 7) << 4))) = val;
      }
    }
    __syncthreads();
  }

  if (tid < 256) {
    out[OUT_H + (size_t)(b0 + myb) * 512 + u0 + myu] = h_last;
    out[OUT_C + (size_t)(b0 + myb) * 512 + u0 + myu] = c_reg;
  }
}

// ---------------------------------------------------------------------------
extern "C" void kernel_launch(void* const* d_in, const int* in_sizes, int n_in,
                              void* d_out, int out_size, void* d_ws, size_t ws_size,
                              hipStream_t stream) {
  const float* x   = (const float*)d_in[0];
  const float* W_w = (const float*)d_in[1];
  const float* W_b = (const float*)d_in[2];
  const float* U_w = (const float*)d_in[3];
  const float* U_b = (const float*)d_in[4];
  const float* A_w = (const float*)d_in[5];
  const float* B_w = (const float*)d_in[6];
  const float* P_w = (const float*)d_in[7];
  char* ws = (char*)d_ws;

  u16*   xb   = (u16*)(ws + WS_XB);
  u16*   Wc   = (u16*)(ws + WS_WC);
  float* bias = (float*)(ws + WS_BIAS);
  u16*   Ubf  = (u16*)(ws + WS_U);
  u16*   Bwbf = (u16*)(ws + WS_BW);
  u16*   Pbf  = (u16*)(ws + WS_P);
  u16*   hbuf = (u16*)(ws + WS_HBUF);
  int*   cnt  = (int*)(ws + WS_CNT);
  u16*   Wxc  = (u16*)(ws + WS_WXC);
  float* outp = (float*)d_out;

  cast_x<<<16384, 256, 0, stream>>>(x, xb);
  prep<<<2048, 256, 0, stream>>>(W_w, W_b, U_w, U_b, A_w, B_w, P_w,
                                 Wc, bias, Ubf, Bwbf, Pbf, cnt);
  gemm_wxc<<<dim3(17, 512), 256, 0, stream>>>(xb, Wc, bias, Wxc);

  void* args[] = { &Wxc, &Ubf, &Bwbf, &Pbf, &hbuf, &cnt, &outp };
  hipError_t e = hipLaunchCooperativeKernel((const void*)recurrent, dim3(128),
                                            dim3(512), args, SMEM_BYTES, stream);
  if (e != hipSuccess) {
    recurrent<<<dim3(128), dim3(512), SMEM_BYTES, stream>>>(Wxc, Ubf, Bwbf, Pbf,
                                                            hbuf, cnt, outp);
  }
}